// Round 6
// baseline (235.592 us; speedup 1.0000x reference)
//
#include <hip/hip_runtime.h>
#include <cstdint>
#include <cstddef>

#define N_NODES 50000
#define N_EDGES 640000
#define DF 128
#define NB_SCAN 49    // ceil(50000/1024)
#define LPAD 136      // LDS row pitch in shorts (128 + 8 pad -> 2-way max aliasing)

typedef __attribute__((ext_vector_type(8))) short bf16x8;
typedef __attribute__((ext_vector_type(4))) float f32x4;

__device__ inline unsigned short f2bf(float f) {            // RNE float->bf16
    unsigned int u = __float_as_uint(f);
    return (unsigned short)((u + 0x7fffu + ((u >> 16) & 1u)) >> 16);
}

// ---------------- setup ----------------
// 1) feat fp32 -> featb bf16 (row-major), 4 elems/thread
// 2) W_pool / W_neigh[:, :128] / W_neigh[:, 128:] -> B-fragment-order bf16:
//    Wf[((c*4+t)*64 + L)*8 + j] = W[c*16+(L&15)][t*32+(L>>4)*8+j]
// 3) zero cursor
#define NF4 (N_NODES * DF / 4)        // 1,600,000
#define NWG (3 * 2048)                // frag groups of 8
__global__ void setup_kernel(const float* __restrict__ feat,
                             const float* __restrict__ W_pool,
                             const float* __restrict__ W_neigh,
                             unsigned short* __restrict__ featb,
                             unsigned short* __restrict__ Wp_f,
                             unsigned short* __restrict__ Wn1_f,
                             unsigned short* __restrict__ Wn2_f,
                             int* __restrict__ cursor) {
    int idx = blockIdx.x * blockDim.x + threadIdx.x;
    if (idx < NF4) {
        float4 v = ((const float4*)feat)[idx];
        ushort4 o;
        o.x = f2bf(v.x); o.y = f2bf(v.y); o.z = f2bf(v.z); o.w = f2bf(v.w);
        ((ushort4*)featb)[idx] = o;
    } else if (idx < NF4 + NWG) {
        int g = idx - NF4;
        int m = g >> 11;            // which matrix
        int r8 = g & 2047;          // (c*4+t)*64 + L
        int L = r8 & 63, t = (r8 >> 6) & 3, c = r8 >> 8;
        int o = c * 16 + (L & 15);
        int kb = t * 32 + (L >> 4) * 8;
        const float* srcp;
        unsigned short* dstp;
        if (m == 0)      { srcp = W_pool  + o * 128 + kb;       dstp = Wp_f;  }
        else if (m == 1) { srcp = W_neigh + o * 256 + kb;       dstp = Wn1_f; }
        else             { srcp = W_neigh + o * 256 + 128 + kb; dstp = Wn2_f; }
        ushort4 lo, hi;
        float4 a = ((const float4*)srcp)[0];
        float4 b = ((const float4*)srcp)[1];
        lo.x = f2bf(a.x); lo.y = f2bf(a.y); lo.z = f2bf(a.z); lo.w = f2bf(a.w);
        hi.x = f2bf(b.x); hi.y = f2bf(b.y); hi.z = f2bf(b.z); hi.w = f2bf(b.w);
        ((ushort4*)(dstp + r8 * 8))[0] = lo;
        ((ushort4*)(dstp + r8 * 8))[1] = hi;
    } else {
        int i = idx - NF4 - NWG;
        if (i < N_NODES) cursor[i] = 0;
    }
}

// ---------------- MFMA GEMM1: hb = bf16(featb @ Wp^T + b_pool) ----------------
// One wave = 16 rows x 128 cols = 8 accumulator tiles of 16x16, K=128.
// No LDS: a_frag and b_frag are direct 16B global loads; B is L1/L2-hot.
__global__ __launch_bounds__(256) void gemm_pool(
    const unsigned short* __restrict__ A, const unsigned short* __restrict__ Bf,
    const float* __restrict__ bias, unsigned short* __restrict__ outb)
{
    int wave = (blockIdx.x * 256 + threadIdx.x) >> 6;
    int lane = threadIdx.x & 63;
    int m0 = wave * 16;
    if (m0 >= N_NODES) return;                 // no barriers in kernel -> safe
    const int n = lane & 15, quad = lane >> 4;

    f32x4 acc[8];
    #pragma unroll
    for (int c = 0; c < 8; ++c) {
        float bv = bias[c * 16 + n];
        acc[c] = (f32x4){bv, bv, bv, bv};
    }

    const unsigned short* aptr = A + (size_t)(m0 + n) * DF + quad * 8;
    #pragma unroll
    for (int t = 0; t < 4; ++t) {
        bf16x8 af = *(const bf16x8*)(aptr + t * 32);
        #pragma unroll
        for (int c = 0; c < 8; ++c) {
            bf16x8 bf = *(const bf16x8*)(Bf + (size_t)((c * 4 + t) * 64 + lane) * 8);
            acc[c] = __builtin_amdgcn_mfma_f32_16x16x32_bf16(af, bf, acc[c], 0, 0, 0);
        }
    }

    // D layout: lane holds D[quad*4+r][c*16+n]
    #pragma unroll
    for (int c = 0; c < 8; ++c)
        #pragma unroll
        for (int r = 0; r < 4; ++r)
            outb[(size_t)(m0 + quad * 4 + r) * DF + c * 16 + n] = f2bf(acc[c][r]);
}

// ---------------- degree histogram (4 edges/thread, int4) ----------------
__global__ void hist_kernel(const int4* __restrict__ dst4, int* __restrict__ cursor) {
    int i = blockIdx.x * blockDim.x + threadIdx.x;
    if (i < N_EDGES / 4) {
        int4 d = dst4[i];
        atomicAdd(&cursor[d.x], 1);
        atomicAdd(&cursor[d.y], 1);
        atomicAdd(&cursor[d.z], 1);
        atomicAdd(&cursor[d.w], 1);
    }
}

// ---------------- 2-stage hierarchical exclusive scan ----------------
__global__ __launch_bounds__(1024) void scan_reduce(const int* __restrict__ cursor,
                                                    int* __restrict__ blocksums) {
    __shared__ int red[1024];
    int t = threadIdx.x;
    int i = blockIdx.x * 1024 + t;
    red[t] = (i < N_NODES) ? cursor[i] : 0;
    __syncthreads();
    #pragma unroll
    for (int off = 512; off > 0; off >>= 1) {
        if (t < off) red[t] += red[t + off];
        __syncthreads();
    }
    if (t == 0) blocksums[blockIdx.x] = red[0];
}

// Each block re-derives the 49-element blocksum scan itself (no scan_tops pass).
__global__ __launch_bounds__(1024) void scan_apply(int* __restrict__ cursor,
                                                   int* __restrict__ offsets,
                                                   const int* __restrict__ blocksums) {
    __shared__ int s[1024];
    __shared__ int bexcl[NB_SCAN + 1];
    int t = threadIdx.x;
    if (t < 64) {
        int orig = (t < NB_SCAN) ? blocksums[t] : 0;
        int v = orig;
        #pragma unroll
        for (int off = 1; off < 64; off <<= 1) {
            int u = __shfl_up(v, off, 64);
            if (t >= off) v += u;
        }
        if (t < NB_SCAN) bexcl[t] = v - orig;        // exclusive prefix
        if (t == NB_SCAN - 1) bexcl[NB_SCAN] = v;    // total = N_EDGES
    }
    int i = blockIdx.x * 1024 + t;
    int v = (i < N_NODES) ? cursor[i] : 0;
    s[t] = v;
    __syncthreads();
    #pragma unroll
    for (int off = 1; off < 1024; off <<= 1) {
        int u = (t >= off) ? s[t - off] : 0;
        __syncthreads();
        s[t] += u;
        __syncthreads();
    }
    if (i < N_NODES) {
        int excl = s[t] - v + bexcl[blockIdx.x];
        offsets[i] = excl;
        cursor[i] = excl;
    }
    if (blockIdx.x == 0 && t == 0) offsets[N_NODES] = bexcl[NB_SCAN];
}

// ---------------- scatter edges into dst-sorted order (packed 8B) ----------
__global__ void scatter_kernel(const int* __restrict__ src, const int* __restrict__ dst,
                               const float* __restrict__ w, int* __restrict__ cursor,
                               uint2* __restrict__ edges) {
    int e = blockIdx.x * blockDim.x + threadIdx.x;
    if (e < N_EDGES) {
        int d = dst[e];
        int pos = atomicAdd(&cursor[d], 1);
        uint2 pk;
        pk.x = (unsigned int)src[e];
        pk.y = __float_as_uint(w[e]);
        edges[pos] = pk;
    }
}

// ---------------- fused: per-node gather-max into LDS, then MFMA gemm2 ------
// One wave owns 16 output rows. Stage 1: for each of its 16 nodes, gather-max
// the incoming messages (half-wave = even/odd edge of a pair, q = col quarter,
// 8 edges/iter -> 4 concurrent 8B gathers) and store the bf16 neigh row into
// the wave's private LDS tile (pitch 136 shorts: 2-way max bank aliasing).
// Stage 2: out = featb @ Wn1^T + neigh(LDS) @ Wn2^T + b_neigh.
// No __syncthreads: each wave touches only its own LDS slice (early-exit safe).
__global__ __launch_bounds__(256) void neigh_gemm(
    const unsigned short* __restrict__ featb,
    const unsigned short* __restrict__ hb,
    const int* __restrict__ offsets,
    const uint2* __restrict__ edges,
    const unsigned short* __restrict__ Wn1_f,
    const unsigned short* __restrict__ Wn2_f,
    const float* __restrict__ bias,
    float* __restrict__ out)
{
    __shared__ unsigned short nl[4][16 * LPAD];
    int wave = (blockIdx.x * 256 + threadIdx.x) >> 6;
    int lane = threadIdx.x & 63;
    int m0 = wave * 16;
    if (m0 >= N_NODES) return;
    unsigned short* myl = &nl[(threadIdx.x >> 6)][0];
    const int half = lane >> 5;      // 0: even edge of pair, 1: odd edge
    const int q = lane & 31;         // column quarter: cols 4q..4q+3

    // ---- stage 1: gather-max 16 nodes into LDS ----
    for (int i = 0; i < 16; ++i) {
        int node = m0 + i;
        int beg = offsets[node], end = offsets[node + 1];
        float4 acc = make_float4(-3.4e38f, -3.4e38f, -3.4e38f, -3.4e38f);
        for (int e = beg; e < end; e += 8) {
            int i1 = min(e + 1, end - 1);
            int i2 = min(e + 2, end - 1);
            int i3 = min(e + 3, end - 1);
            int i4 = min(e + 4, end - 1);
            int i5 = min(e + 5, end - 1);
            int i6 = min(e + 6, end - 1);
            int i7 = min(e + 7, end - 1);
            uint2 e0 = edges[e],  e1 = edges[i1], e2 = edges[i2], e3 = edges[i3];
            uint2 e4 = edges[i4], e5 = edges[i5], e6 = edges[i6], e7 = edges[i7];
            uint2 mA = half ? e1 : e0;
            uint2 mB = half ? e3 : e2;
            uint2 mC = half ? e5 : e4;
            uint2 mD = half ? e7 : e6;
            float wA = __uint_as_float(mA.y);
            float wB = __uint_as_float(mB.y);
            float wC = __uint_as_float(mC.y);
            float wD = __uint_as_float(mD.y);
            uint2 pA = *(const uint2*)(hb + (size_t)mA.x * DF + q * 4);
            uint2 pB = *(const uint2*)(hb + (size_t)mB.x * DF + q * 4);
            uint2 pC = *(const uint2*)(hb + (size_t)mC.x * DF + q * 4);
            uint2 pD = *(const uint2*)(hb + (size_t)mD.x * DF + q * 4);
            acc.x = fmaxf(acc.x, __uint_as_float(pA.x << 16)          * wA);
            acc.y = fmaxf(acc.y, __uint_as_float(pA.x & 0xffff0000u)  * wA);
            acc.z = fmaxf(acc.z, __uint_as_float(pA.y << 16)          * wA);
            acc.w = fmaxf(acc.w, __uint_as_float(pA.y & 0xffff0000u)  * wA);
            acc.x = fmaxf(acc.x, __uint_as_float(pB.x << 16)          * wB);
            acc.y = fmaxf(acc.y, __uint_as_float(pB.x & 0xffff0000u)  * wB);
            acc.z = fmaxf(acc.z, __uint_as_float(pB.y << 16)          * wB);
            acc.w = fmaxf(acc.w, __uint_as_float(pB.y & 0xffff0000u)  * wB);
            acc.x = fmaxf(acc.x, __uint_as_float(pC.x << 16)          * wC);
            acc.y = fmaxf(acc.y, __uint_as_float(pC.x & 0xffff0000u)  * wC);
            acc.z = fmaxf(acc.z, __uint_as_float(pC.y << 16)          * wC);
            acc.w = fmaxf(acc.w, __uint_as_float(pC.y & 0xffff0000u)  * wC);
            acc.x = fmaxf(acc.x, __uint_as_float(pD.x << 16)          * wD);
            acc.y = fmaxf(acc.y, __uint_as_float(pD.x & 0xffff0000u)  * wD);
            acc.z = fmaxf(acc.z, __uint_as_float(pD.y << 16)          * wD);
            acc.w = fmaxf(acc.w, __uint_as_float(pD.y & 0xffff0000u)  * wD);
        }
        float4 o;
        o.x = fmaxf(acc.x, __shfl_xor(acc.x, 32));
        o.y = fmaxf(acc.y, __shfl_xor(acc.y, 32));
        o.z = fmaxf(acc.z, __shfl_xor(acc.z, 32));
        o.w = fmaxf(acc.w, __shfl_xor(acc.w, 32));
        if (beg == end) o = make_float4(0.f, 0.f, 0.f, 0.f);
        if (half == 0) {
            ushort4 ob;
            ob.x = f2bf(o.x); ob.y = f2bf(o.y); ob.z = f2bf(o.z); ob.w = f2bf(o.w);
            *(ushort4*)(myl + i * LPAD + q * 4) = ob;
        }
    }
    // intra-wave ds_write -> ds_read ordering handled by compiler waitcnt

    // ---- stage 2: MFMA ----
    const int n = lane & 15, quad = lane >> 4;
    f32x4 acc[8];
    #pragma unroll
    for (int c = 0; c < 8; ++c) {
        float bv = bias[c * 16 + n];
        acc[c] = (f32x4){bv, bv, bv, bv};
    }

    // phase 0: A = featb rows (global)
    const unsigned short* aptr = featb + (size_t)(m0 + n) * DF + quad * 8;
    #pragma unroll
    for (int t = 0; t < 4; ++t) {
        bf16x8 af = *(const bf16x8*)(aptr + t * 32);
        #pragma unroll
        for (int c = 0; c < 8; ++c) {
            bf16x8 bf = *(const bf16x8*)(Wn1_f + (size_t)((c * 4 + t) * 64 + lane) * 8);
            acc[c] = __builtin_amdgcn_mfma_f32_16x16x32_bf16(af, bf, acc[c], 0, 0, 0);
        }
    }
    // phase 1: A = neigh rows (LDS)
    #pragma unroll
    for (int t = 0; t < 4; ++t) {
        bf16x8 af = *(const bf16x8*)(myl + n * LPAD + t * 32 + quad * 8);
        #pragma unroll
        for (int c = 0; c < 8; ++c) {
            bf16x8 bf = *(const bf16x8*)(Wn2_f + (size_t)((c * 4 + t) * 64 + lane) * 8);
            acc[c] = __builtin_amdgcn_mfma_f32_16x16x32_bf16(af, bf, acc[c], 0, 0, 0);
        }
    }

    // D layout: lane holds D[quad*4+r][c*16+n]
    #pragma unroll
    for (int c = 0; c < 8; ++c)
        #pragma unroll
        for (int r = 0; r < 4; ++r)
            out[(size_t)(m0 + quad * 4 + r) * DF + c * 16 + n] = acc[c][r];
}

extern "C" void kernel_launch(void* const* d_in, const int* in_sizes, int n_in,
                              void* d_out, int out_size, void* d_ws, size_t ws_size,
                              hipStream_t stream) {
    const float* feat    = (const float*)d_in[0];
    const float* weight  = (const float*)d_in[1];
    const int*   src     = (const int*)d_in[2];
    const int*   dst     = (const int*)d_in[3];
    const float* W_pool  = (const float*)d_in[4];
    const float* b_pool  = (const float*)d_in[5];
    const float* W_neigh = (const float*)d_in[6];
    const float* b_neigh = (const float*)d_in[7];
    float* out = (float*)d_out;

    char* ws = (char*)d_ws;
    unsigned short* featb  = (unsigned short*)(ws);              // 12,800,000 B
    unsigned short* hb     = (unsigned short*)(ws + 12800000);   // 12,800,000 B
    unsigned short* Wp_f   = (unsigned short*)(ws + 25600000);   // 32,768 B
    unsigned short* Wn1_f  = (unsigned short*)(ws + 25632768);   // 32,768 B
    unsigned short* Wn2_f  = (unsigned short*)(ws + 25665536);   // 32,768 B
    int*   offsets   = (int*)  (ws + 25698304);                  // 200,064 B
    int*   cursor    = (int*)  (ws + 25898368);                  // 200,064 B
    uint2* edges     = (uint2*)(ws + 26098432);                  // 5,120,000 B
    int*   blocksums = (int*)  (ws + 31218432);                  // 256 B -> ~31.2 MB

    const int NSETUP = NF4 + NWG + N_NODES;
    setup_kernel<<<(NSETUP + 255) / 256, 256, 0, stream>>>(
        feat, W_pool, W_neigh, featb, Wp_f, Wn1_f, Wn2_f, cursor);

    const int GEMM_BLOCKS = ((N_NODES + 15) / 16 + 3) / 4;   // 4 waves/block

    // hb = bf16(featb @ Wp^T + b_pool)
    gemm_pool<<<GEMM_BLOCKS, 256, 0, stream>>>(featb, Wp_f, b_pool, hb);

    hist_kernel<<<(N_EDGES / 4 + 255) / 256, 256, 0, stream>>>((const int4*)dst, cursor);

    scan_reduce<<<NB_SCAN, 1024, 0, stream>>>(cursor, blocksums);
    scan_apply<<<NB_SCAN, 1024, 0, stream>>>(cursor, offsets, blocksums);

    scatter_kernel<<<(N_EDGES + 255) / 256, 256, 0, stream>>>(
        src, dst, weight, cursor, edges);

    // out = featb @ Wn1^T + segment_max-gather(LDS) @ Wn2^T + b_neigh
    neigh_gemm<<<GEMM_BLOCKS, 256, 0, stream>>>(
        featb, hb, offsets, edges, Wn1_f, Wn2_f, b_neigh, out);
}

// Round 7
// 230.128 us; speedup vs baseline: 1.0237x; 1.0237x over previous
//
#include <hip/hip_runtime.h>
#include <cstdint>
#include <cstddef>

#define N_NODES 50000
#define N_EDGES 640000
#define DF 128

typedef __attribute__((ext_vector_type(8))) short bf16x8;
typedef __attribute__((ext_vector_type(4))) float f32x4;

__device__ inline unsigned short f2bf(float f) {            // RNE float->bf16
    unsigned int u = __float_as_uint(f);
    return (unsigned short)((u + 0x7fffu + ((u >> 16) & 1u)) >> 16);
}

// ================= K1: setup (feat->bf16, W->frag order) || hist =============
// idx < NF4                : featb conversion (float4 -> ushort4)
// idx < NF4+NWG            : W fragment packing
// else                     : histogram over dst (4 edges via int4)
#define NF4 (N_NODES * DF / 4)        // 1,600,000
#define NWG (3 * 2048)                // frag groups of 8
#define K1_THREADS (NF4 + NWG + N_EDGES / 4)   // 1,766,144 = 6899 * 256
__global__ __launch_bounds__(256) void setup_hist(
    const float* __restrict__ feat,
    const float* __restrict__ W_pool,
    const float* __restrict__ W_neigh,
    const int4* __restrict__ dst4,
    unsigned short* __restrict__ featb,
    unsigned short* __restrict__ Wp_f,
    unsigned short* __restrict__ Wn1_f,
    unsigned short* __restrict__ Wn2_f,
    int* __restrict__ cursor)           // pre-zeroed via hipMemsetAsync
{
    int idx = blockIdx.x * blockDim.x + threadIdx.x;
    if (idx < NF4) {
        float4 v = ((const float4*)feat)[idx];
        ushort4 o;
        o.x = f2bf(v.x); o.y = f2bf(v.y); o.z = f2bf(v.z); o.w = f2bf(v.w);
        ((ushort4*)featb)[idx] = o;
    } else if (idx < NF4 + NWG) {
        int g = idx - NF4;
        int m = g >> 11;            // which matrix
        int r8 = g & 2047;          // (c*4+t)*64 + L
        int L = r8 & 63, t = (r8 >> 6) & 3, c = r8 >> 8;
        int o = c * 16 + (L & 15);
        int kb = t * 32 + (L >> 4) * 8;
        const float* srcp;
        unsigned short* dstp;
        if (m == 0)      { srcp = W_pool  + o * 128 + kb;       dstp = Wp_f;  }
        else if (m == 1) { srcp = W_neigh + o * 256 + kb;       dstp = Wn1_f; }
        else             { srcp = W_neigh + o * 256 + 128 + kb; dstp = Wn2_f; }
        ushort4 lo, hi;
        float4 a = ((const float4*)srcp)[0];
        float4 b = ((const float4*)srcp)[1];
        lo.x = f2bf(a.x); lo.y = f2bf(a.y); lo.z = f2bf(a.z); lo.w = f2bf(a.w);
        hi.x = f2bf(b.x); hi.y = f2bf(b.y); hi.z = f2bf(b.z); hi.w = f2bf(b.w);
        ((ushort4*)(dstp + r8 * 8))[0] = lo;
        ((ushort4*)(dstp + r8 * 8))[1] = hi;
    } else {
        int j = idx - (NF4 + NWG);
        if (j < N_EDGES / 4) {
            int4 d = dst4[j];
            atomicAdd(&cursor[d.x], 1);
            atomicAdd(&cursor[d.y], 1);
            atomicAdd(&cursor[d.z], 1);
            atomicAdd(&cursor[d.w], 1);
        }
    }
}

// ================= K2: gemm_pool || exclusive scan ===========================
// blocks [0, GEMM_BLOCKS): hb = bf16(featb @ Wp^T + b_pool), 1 wave = 16 rows
// blocks [GEMM_BLOCKS, +SCAN_BLOCKS): block bid scans nodes [bid*256, +256):
//   prefix base = redundant sum of cursor[0 .. bid*256) (L2-hot, <=195 ld/thr),
//   own chunk via LDS Hillis-Steele. Writes offsets + wcursor (cursor stays
//   read-only -> no cross-block race).
#define GEMM_BLOCKS 782    // ceil((50000/16)/4)
#define SCAN_BLOCKS 196    // ceil(50000/256)
__global__ __launch_bounds__(256) void gemm_scan(
    const unsigned short* __restrict__ featb,
    const unsigned short* __restrict__ Wp_f,
    const float* __restrict__ b_pool,
    unsigned short* __restrict__ hb,
    const int* __restrict__ cursor,
    int* __restrict__ offsets,
    int* __restrict__ wcursor)
{
    if (blockIdx.x < GEMM_BLOCKS) {
        int wave = (blockIdx.x * 256 + threadIdx.x) >> 6;
        int lane = threadIdx.x & 63;
        int m0 = wave * 16;
        if (m0 >= N_NODES) return;             // no barriers on this path
        const int n = lane & 15, quad = lane >> 4;

        f32x4 acc[8];
        #pragma unroll
        for (int c = 0; c < 8; ++c) {
            float bv = b_pool[c * 16 + n];
            acc[c] = (f32x4){bv, bv, bv, bv};
        }
        const unsigned short* aptr = featb + (size_t)(m0 + n) * DF + quad * 8;
        #pragma unroll
        for (int t = 0; t < 4; ++t) {
            bf16x8 af = *(const bf16x8*)(aptr + t * 32);
            #pragma unroll
            for (int c = 0; c < 8; ++c) {
                bf16x8 bf = *(const bf16x8*)(Wp_f + (size_t)((c * 4 + t) * 64 + lane) * 8);
                acc[c] = __builtin_amdgcn_mfma_f32_16x16x32_bf16(af, bf, acc[c], 0, 0, 0);
            }
        }
        // D layout: lane holds D[quad*4+r][c*16+n]
        #pragma unroll
        for (int c = 0; c < 8; ++c)
            #pragma unroll
            for (int r = 0; r < 4; ++r)
                hb[(size_t)(m0 + quad * 4 + r) * DF + c * 16 + n] = f2bf(acc[c][r]);
    } else {
        __shared__ int pre[256];
        __shared__ int s[256];
        int bid = blockIdx.x - GEMM_BLOCKS;
        int t = threadIdx.x;
        int base = bid * 256;
        // prefix base: sum of cursor[0..base)
        int ps = 0;
        for (int j = t; j < base; j += 256) ps += cursor[j];
        pre[t] = ps;
        __syncthreads();
        #pragma unroll
        for (int off = 128; off > 0; off >>= 1) {
            if (t < off) pre[t] += pre[t + off];
            __syncthreads();
        }
        int basesum = pre[0];
        int i = base + t;
        int v = (i < N_NODES) ? cursor[i] : 0;
        s[t] = v;
        __syncthreads();
        #pragma unroll
        for (int off = 1; off < 256; off <<= 1) {
            int u = (t >= off) ? s[t - off] : 0;
            __syncthreads();
            s[t] += u;
            __syncthreads();
        }
        if (i < N_NODES) {
            int excl = basesum + s[t] - v;
            offsets[i] = excl;
            wcursor[i] = excl;
            if (i == N_NODES - 1) offsets[N_NODES] = excl + v;
        }
    }
}

// ================= K3: scatter edges into dst-sorted order (packed 8B) ======
__global__ void scatter_kernel(const int* __restrict__ src, const int* __restrict__ dst,
                               const float* __restrict__ w, int* __restrict__ wcursor,
                               uint2* __restrict__ edges) {
    int e = blockIdx.x * blockDim.x + threadIdx.x;
    if (e < N_EDGES) {
        int d = dst[e];
        int pos = atomicAdd(&wcursor[d], 1);
        uint2 pk;
        pk.x = (unsigned int)src[e];
        pk.y = __float_as_uint(w[e]);
        edges[pos] = pk;
    }
}

// ================= K4: per-node max over incoming messages (1 wave/node) ====
// hb bf16 (row = 256 B). Half-wave gathers even/odd edge of a pair; 8 edges
// per iteration -> 4 independent 8B gathers in flight. Output bf16.
__global__ __launch_bounds__(256) void neigh_max_kernel(
    const unsigned short* __restrict__ hb, const int* __restrict__ offsets,
    const uint2* __restrict__ edges,
    unsigned short* __restrict__ neighb)
{
    int gwave = (blockIdx.x * 256 + threadIdx.x) >> 6;
    if (gwave >= N_NODES) return;
    int node = __builtin_amdgcn_readfirstlane(gwave);
    int lane = threadIdx.x & 63;
    const int half = lane >> 5;      // 0: even edge of pair, 1: odd edge
    const int q = lane & 31;         // column quarter: cols 4q..4q+3

    int beg = offsets[node], end = offsets[node + 1];
    float4 acc = make_float4(-3.4e38f, -3.4e38f, -3.4e38f, -3.4e38f);

    for (int e = beg; e < end; e += 8) {
        int i1 = min(e + 1, end - 1);
        int i2 = min(e + 2, end - 1);
        int i3 = min(e + 3, end - 1);
        int i4 = min(e + 4, end - 1);
        int i5 = min(e + 5, end - 1);
        int i6 = min(e + 6, end - 1);
        int i7 = min(e + 7, end - 1);
        uint2 e0 = edges[e],  e1 = edges[i1], e2 = edges[i2], e3 = edges[i3];
        uint2 e4 = edges[i4], e5 = edges[i5], e6 = edges[i6], e7 = edges[i7];
        uint2 mA = half ? e1 : e0;
        uint2 mB = half ? e3 : e2;
        uint2 mC = half ? e5 : e4;
        uint2 mD = half ? e7 : e6;
        float wA = __uint_as_float(mA.y);
        float wB = __uint_as_float(mB.y);
        float wC = __uint_as_float(mC.y);
        float wD = __uint_as_float(mD.y);
        uint2 pA = *(const uint2*)(hb + (size_t)mA.x * DF + q * 4);
        uint2 pB = *(const uint2*)(hb + (size_t)mB.x * DF + q * 4);
        uint2 pC = *(const uint2*)(hb + (size_t)mC.x * DF + q * 4);
        uint2 pD = *(const uint2*)(hb + (size_t)mD.x * DF + q * 4);
        acc.x = fmaxf(acc.x, __uint_as_float(pA.x << 16)          * wA);
        acc.y = fmaxf(acc.y, __uint_as_float(pA.x & 0xffff0000u)  * wA);
        acc.z = fmaxf(acc.z, __uint_as_float(pA.y << 16)          * wA);
        acc.w = fmaxf(acc.w, __uint_as_float(pA.y & 0xffff0000u)  * wA);
        acc.x = fmaxf(acc.x, __uint_as_float(pB.x << 16)          * wB);
        acc.y = fmaxf(acc.y, __uint_as_float(pB.x & 0xffff0000u)  * wB);
        acc.z = fmaxf(acc.z, __uint_as_float(pB.y << 16)          * wB);
        acc.w = fmaxf(acc.w, __uint_as_float(pB.y & 0xffff0000u)  * wB);
        acc.x = fmaxf(acc.x, __uint_as_float(pC.x << 16)          * wC);
        acc.y = fmaxf(acc.y, __uint_as_float(pC.x & 0xffff0000u)  * wC);
        acc.z = fmaxf(acc.z, __uint_as_float(pC.y << 16)          * wC);
        acc.w = fmaxf(acc.w, __uint_as_float(pC.y & 0xffff0000u)  * wC);
        acc.x = fmaxf(acc.x, __uint_as_float(pD.x << 16)          * wD);
        acc.y = fmaxf(acc.y, __uint_as_float(pD.x & 0xffff0000u)  * wD);
        acc.z = fmaxf(acc.z, __uint_as_float(pD.y << 16)          * wD);
        acc.w = fmaxf(acc.w, __uint_as_float(pD.y & 0xffff0000u)  * wD);
    }

    float4 o;
    o.x = fmaxf(acc.x, __shfl_xor(acc.x, 32));
    o.y = fmaxf(acc.y, __shfl_xor(acc.y, 32));
    o.z = fmaxf(acc.z, __shfl_xor(acc.z, 32));
    o.w = fmaxf(acc.w, __shfl_xor(acc.w, 32));
    if (beg == end) o = make_float4(0.f, 0.f, 0.f, 0.f);
    if (half == 0) {
        ushort4 ob;
        ob.x = f2bf(o.x); ob.y = f2bf(o.y); ob.z = f2bf(o.z); ob.w = f2bf(o.w);
        *(ushort4*)(neighb + (size_t)node * DF + q * 4) = ob;
    }
}

// ================= K5: out = featb@Wn1^T + neighb@Wn2^T + b_neigh (fp32) ====
__global__ __launch_bounds__(256) void gemm_out(
    const unsigned short* __restrict__ featb,
    const unsigned short* __restrict__ neighb,
    const unsigned short* __restrict__ Wn1_f,
    const unsigned short* __restrict__ Wn2_f,
    const float* __restrict__ bias,
    float* __restrict__ out)
{
    int wave = (blockIdx.x * 256 + threadIdx.x) >> 6;
    int lane = threadIdx.x & 63;
    int m0 = wave * 16;
    if (m0 >= N_NODES) return;
    const int n = lane & 15, quad = lane >> 4;

    f32x4 acc[8];
    #pragma unroll
    for (int c = 0; c < 8; ++c) {
        float bv = bias[c * 16 + n];
        acc[c] = (f32x4){bv, bv, bv, bv};
    }

    const unsigned short* a0 = featb  + (size_t)(m0 + n) * DF + quad * 8;
    const unsigned short* a1 = neighb + (size_t)(m0 + n) * DF + quad * 8;
    #pragma unroll
    for (int t = 0; t < 4; ++t) {
        bf16x8 af = *(const bf16x8*)(a0 + t * 32);
        #pragma unroll
        for (int c = 0; c < 8; ++c) {
            bf16x8 bf = *(const bf16x8*)(Wn1_f + (size_t)((c * 4 + t) * 64 + lane) * 8);
            acc[c] = __builtin_amdgcn_mfma_f32_16x16x32_bf16(af, bf, acc[c], 0, 0, 0);
        }
    }
    #pragma unroll
    for (int t = 0; t < 4; ++t) {
        bf16x8 af = *(const bf16x8*)(a1 + t * 32);
        #pragma unroll
        for (int c = 0; c < 8; ++c) {
            bf16x8 bf = *(const bf16x8*)(Wn2_f + (size_t)((c * 4 + t) * 64 + lane) * 8);
            acc[c] = __builtin_amdgcn_mfma_f32_16x16x32_bf16(af, bf, acc[c], 0, 0, 0);
        }
    }

    // D layout: lane holds D[quad*4+r][c*16+n]
    #pragma unroll
    for (int c = 0; c < 8; ++c)
        #pragma unroll
        for (int r = 0; r < 4; ++r)
            out[(size_t)(m0 + quad * 4 + r) * DF + c * 16 + n] = acc[c][r];
}

extern "C" void kernel_launch(void* const* d_in, const int* in_sizes, int n_in,
                              void* d_out, int out_size, void* d_ws, size_t ws_size,
                              hipStream_t stream) {
    const float* feat    = (const float*)d_in[0];
    const float* weight  = (const float*)d_in[1];
    const int*   src     = (const int*)d_in[2];
    const int*   dst     = (const int*)d_in[3];
    const float* W_pool  = (const float*)d_in[4];
    const float* b_pool  = (const float*)d_in[5];
    const float* W_neigh = (const float*)d_in[6];
    const float* b_neigh = (const float*)d_in[7];
    float* out = (float*)d_out;

    char* ws = (char*)d_ws;
    unsigned short* featb  = (unsigned short*)(ws);              // 12,800,000 B
    unsigned short* hb     = (unsigned short*)(ws + 12800000);   // 12,800,000 B
    unsigned short* neighb = (unsigned short*)(ws + 25600000);   // 12,800,000 B
    unsigned short* Wp_f   = (unsigned short*)(ws + 38400000);   // 32,768 B
    unsigned short* Wn1_f  = (unsigned short*)(ws + 38432768);   // 32,768 B
    unsigned short* Wn2_f  = (unsigned short*)(ws + 38465536);   // 32,768 B
    int*   offsets   = (int*)  (ws + 38498304);                  // 200,064 B
    int*   cursor    = (int*)  (ws + 38698368);                  // 200,064 B
    int*   wcursor   = (int*)  (ws + 38898432);                  // 200,064 B
    uint2* edges     = (uint2*)(ws + 39098496);                  // 5,120,000 B -> ~44.2 MB

    // cursor = 0 (DMA; overlaps nothing, ~0 cost)
    hipMemsetAsync(cursor, 0, N_NODES * sizeof(int), stream);

    // K1: featb/W-frag conversion || dst histogram
    setup_hist<<<K1_THREADS / 256, 256, 0, stream>>>(
        feat, W_pool, W_neigh, (const int4*)dst,
        featb, Wp_f, Wn1_f, Wn2_f, cursor);

    // K2: hb = bf16(featb @ Wp^T + b_pool) || exclusive-scan(degrees)
    gemm_scan<<<GEMM_BLOCKS + SCAN_BLOCKS, 256, 0, stream>>>(
        featb, Wp_f, b_pool, hb, cursor, offsets, wcursor);

    // K3: counting-sort scatter (packed 8B edge records)
    scatter_kernel<<<(N_EDGES + 255) / 256, 256, 0, stream>>>(
        src, dst, weight, wcursor, edges);

    // K4: neighb = bf16(segment_max(hb[src]*w, dst)), 0 for empty
    neigh_max_kernel<<<(N_NODES + 3) / 4, 256, 0, stream>>>(hb, offsets, edges, neighb);

    // K5: out = featb @ Wn1^T + neighb @ Wn2^T + b_neigh
    gemm_out<<<GEMM_BLOCKS, 256, 0, stream>>>(
        featb, neighb, Wn1_f, Wn2_f, b_neigh, out);
}

// Round 8
// 163.391 us; speedup vs baseline: 1.4419x; 1.4084x over previous
//
#include <hip/hip_runtime.h>
#include <cstdint>
#include <cstddef>

#define N_NODES 50000
#define N_EDGES 640000
#define DF 128

#define NBUCK 196          // buckets of 256 nodes: bucket = dst >> 8
#define BCAP  6144         // staging capacity per bucket (mean 3265, +50 sigma)
#define PA_BLOCKS 250      // PassA blocks, 2560 edges each (250*2560 = 640000)

typedef __attribute__((ext_vector_type(8))) short bf16x8;
typedef __attribute__((ext_vector_type(4))) float f32x4;

__device__ inline unsigned short f2bf(float f) {            // RNE float->bf16
    unsigned int u = __float_as_uint(f);
    return (unsigned short)((u + 0x7fffu + ((u >> 16) & 1u)) >> 16);
}

// ================= K1: PassA (coarse bucket sort) || setup ===================
// blocks [0,250):        PassA — bin 2560 edges into 196 coarse buckets.
//   LDS count -> one global atomic per (block,bucket) reserves a contiguous
//   run -> packed 8B records {src|dstlocal<<16, w} stored in ~100B runs.
// blocks [250,6500):     featb = bf16(feat)
// blocks [6500,6524):    W fragments (B-operand order for 16x16x32 MFMA)
#define NF4 (N_NODES * DF / 4)        // 1,600,000
#define NWG (3 * 2048)
__global__ __launch_bounds__(256) void k1_setup_bucket(
    const float* __restrict__ feat,
    const float* __restrict__ W_pool,
    const float* __restrict__ W_neigh,
    const int* __restrict__ src,
    const int* __restrict__ dst,
    const float* __restrict__ w,
    unsigned short* __restrict__ featb,
    unsigned short* __restrict__ Wp_f,
    unsigned short* __restrict__ Wn1_f,
    unsigned short* __restrict__ Wn2_f,
    int* __restrict__ bucketcnt,        // pre-zeroed via hipMemsetAsync
    uint2* __restrict__ staging)
{
    int bid = blockIdx.x;
    int t = threadIdx.x;
    if (bid < PA_BLOCKS) {
        __shared__ int cnt[NBUCK];
        __shared__ int runbase[NBUCK];
        int base = bid * 2560;
        if (t < NBUCK) cnt[t] = 0;
        __syncthreads();
        uint2 rec[10];
        int bk[10];
        #pragma unroll
        for (int i = 0; i < 10; ++i) {
            int e = base + i * 256 + t;
            int s = src[e], d = dst[e];
            bk[i] = d >> 8;
            rec[i].x = (unsigned int)s | ((unsigned int)(d & 255) << 16);
            rec[i].y = __float_as_uint(w[e]);
            atomicAdd(&cnt[bk[i]], 1);
        }
        __syncthreads();
        if (t < NBUCK) {
            runbase[t] = atomicAdd(&bucketcnt[t], cnt[t]);
            cnt[t] = 0;                 // reuse as within-run cursor
        }
        __syncthreads();
        #pragma unroll
        for (int i = 0; i < 10; ++i) {
            int r = atomicAdd(&cnt[bk[i]], 1);
            int pos = runbase[bk[i]] + r;
            if (pos < BCAP) staging[bk[i] * BCAP + pos] = rec[i];
        }
    } else if (bid < 250 + NF4 / 256) {
        int idx = (bid - PA_BLOCKS) * 256 + t;
        float4 v = ((const float4*)feat)[idx];
        ushort4 o;
        o.x = f2bf(v.x); o.y = f2bf(v.y); o.z = f2bf(v.z); o.w = f2bf(v.w);
        ((ushort4*)featb)[idx] = o;
    } else {
        int g = (bid - PA_BLOCKS - NF4 / 256) * 256 + t;   // < NWG
        int m = g >> 11;
        int r8 = g & 2047;          // (c*4+tt)*64 + L
        int L = r8 & 63, tt = (r8 >> 6) & 3, c = r8 >> 8;
        int o = c * 16 + (L & 15);
        int kb = tt * 32 + (L >> 4) * 8;
        const float* srcp;
        unsigned short* dstp;
        if (m == 0)      { srcp = W_pool  + o * 128 + kb;       dstp = Wp_f;  }
        else if (m == 1) { srcp = W_neigh + o * 256 + kb;       dstp = Wn1_f; }
        else             { srcp = W_neigh + o * 256 + 128 + kb; dstp = Wn2_f; }
        ushort4 lo, hi;
        float4 a = ((const float4*)srcp)[0];
        float4 b = ((const float4*)srcp)[1];
        lo.x = f2bf(a.x); lo.y = f2bf(a.y); lo.z = f2bf(a.z); lo.w = f2bf(a.w);
        hi.x = f2bf(b.x); hi.y = f2bf(b.y); hi.z = f2bf(b.z); hi.w = f2bf(b.w);
        ((ushort4*)(dstp + r8 * 8))[0] = lo;
        ((ushort4*)(dstp + r8 * 8))[1] = hi;
    }
}

// ================= K2: gemm_pool || PassB (per-bucket fine sort) =============
// blocks [0,196):  gemm_pool — hb = bf16(featb @ Wp^T + b_pool), 16 waves/blk
// blocks [196,392): PassB — bucket b: base = prefix(bucketcnt), count+scan
//   per-node degrees in LDS, write offsets, re-scatter records into final
//   dst-sorted edges[] (stores confined to this block's ~26KB region).
#define GEMMB 196          // ceil(3125 waves / 16)
__global__ __launch_bounds__(1024) void k2_gemm_passb(
    const unsigned short* __restrict__ featb,
    const unsigned short* __restrict__ Wp_f,
    const float* __restrict__ b_pool,
    unsigned short* __restrict__ hb,
    const int* __restrict__ bucketcnt,
    const uint2* __restrict__ staging,
    int* __restrict__ offsets,
    uint2* __restrict__ edges)
{
    int t = threadIdx.x;
    if (blockIdx.x < GEMMB) {
        int wave = blockIdx.x * 16 + (t >> 6);
        int lane = t & 63;
        int m0 = wave * 16;
        if (m0 >= N_NODES) return;          // no barriers on this path
        const int n = lane & 15, quad = lane >> 4;

        f32x4 acc[8];
        #pragma unroll
        for (int c = 0; c < 8; ++c) {
            float bv = b_pool[c * 16 + n];
            acc[c] = (f32x4){bv, bv, bv, bv};
        }
        const unsigned short* aptr = featb + (size_t)(m0 + n) * DF + quad * 8;
        #pragma unroll
        for (int tt = 0; tt < 4; ++tt) {
            bf16x8 af = *(const bf16x8*)(aptr + tt * 32);
            #pragma unroll
            for (int c = 0; c < 8; ++c) {
                bf16x8 bf = *(const bf16x8*)(Wp_f + (size_t)((c * 4 + tt) * 64 + lane) * 8);
                acc[c] = __builtin_amdgcn_mfma_f32_16x16x32_bf16(af, bf, acc[c], 0, 0, 0);
            }
        }
        #pragma unroll
        for (int c = 0; c < 8; ++c)
            #pragma unroll
            for (int r = 0; r < 4; ++r)
                hb[(size_t)(m0 + quad * 4 + r) * DF + c * 16 + n] = f2bf(acc[c][r]);
    } else {
        __shared__ int dcnt[256];       // per-node count, then global cursor
        __shared__ int sc[256];         // scan scratch
        __shared__ int bc[256];         // bucket counts
        int b = blockIdx.x - GEMMB;     // 0..195

        if (t < 256) { dcnt[t] = 0; bc[t] = (t < NBUCK) ? bucketcnt[t] : 0; sc[t] = (t < NBUCK) ? bc[t] : 0; }
        __syncthreads();
        // exclusive prefix of bucket counts (Hillis-Steele over 256)
        #pragma unroll
        for (int off = 1; off < 256; off <<= 1) {
            int u = (t < 256 && t >= off) ? sc[t - off] : 0;
            __syncthreads();
            if (t < 256) sc[t] += u;
            __syncthreads();
        }
        int mybase = (b > 0) ? sc[b - 1] : 0;
        int cnt = bc[b];
        __syncthreads();                 // sc about to be reused

        // load my staged records, count per-node degrees
        uint2 rec[6];
        int nit = (cnt + 1023) >> 10;
        for (int i = 0; i < nit; ++i) {
            int idx = i * 1024 + t;
            if (idx < cnt) {
                rec[i] = staging[(size_t)b * BCAP + idx];
                atomicAdd(&dcnt[(rec[i].x >> 16) & 255], 1);
            }
        }
        __syncthreads();
        if (t < 256) sc[t] = dcnt[t];
        __syncthreads();
        #pragma unroll
        for (int off = 1; off < 256; off <<= 1) {
            int u = (t < 256 && t >= off) ? sc[t - off] : 0;
            __syncthreads();
            if (t < 256) sc[t] += u;
            __syncthreads();
        }
        if (t < 256) {
            int node = b * 256 + t;
            int excl = sc[t] - dcnt[t];
            if (node < N_NODES) offsets[node] = mybase + excl;
            dcnt[t] = mybase + excl;     // repurpose: global write cursor
        }
        if (b == NBUCK - 1 && t == 0) offsets[N_NODES] = mybase + cnt;
        __syncthreads();
        for (int i = 0; i < nit; ++i) {
            int idx = i * 1024 + t;
            if (idx < cnt) {
                int dl = (rec[i].x >> 16) & 255;
                int pos = atomicAdd(&dcnt[dl], 1);
                uint2 fin;
                fin.x = rec[i].x & 0xFFFFu;     // src
                fin.y = rec[i].y;               // w bits
                edges[pos] = fin;
            }
        }
    }
}

// ================= K3: per-node max over incoming messages (1 wave/node) ====
// hb bf16 (row = 256 B). Half-wave gathers even/odd edge of a pair; 8 edges
// per iteration -> 4 independent 8B gathers in flight. Output bf16.
__global__ __launch_bounds__(256) void neigh_max_kernel(
    const unsigned short* __restrict__ hb, const int* __restrict__ offsets,
    const uint2* __restrict__ edges,
    unsigned short* __restrict__ neighb)
{
    int gwave = (blockIdx.x * 256 + threadIdx.x) >> 6;
    if (gwave >= N_NODES) return;
    int node = __builtin_amdgcn_readfirstlane(gwave);
    int lane = threadIdx.x & 63;
    const int half = lane >> 5;      // 0: even edge of pair, 1: odd edge
    const int q = lane & 31;         // column quarter: cols 4q..4q+3

    int beg = offsets[node], end = offsets[node + 1];
    float4 acc = make_float4(-3.4e38f, -3.4e38f, -3.4e38f, -3.4e38f);

    for (int e = beg; e < end; e += 8) {
        int i1 = min(e + 1, end - 1);
        int i2 = min(e + 2, end - 1);
        int i3 = min(e + 3, end - 1);
        int i4 = min(e + 4, end - 1);
        int i5 = min(e + 5, end - 1);
        int i6 = min(e + 6, end - 1);
        int i7 = min(e + 7, end - 1);
        uint2 e0 = edges[e],  e1 = edges[i1], e2 = edges[i2], e3 = edges[i3];
        uint2 e4 = edges[i4], e5 = edges[i5], e6 = edges[i6], e7 = edges[i7];
        uint2 mA = half ? e1 : e0;
        uint2 mB = half ? e3 : e2;
        uint2 mC = half ? e5 : e4;
        uint2 mD = half ? e7 : e6;
        float wA = __uint_as_float(mA.y);
        float wB = __uint_as_float(mB.y);
        float wC = __uint_as_float(mC.y);
        float wD = __uint_as_float(mD.y);
        uint2 pA = *(const uint2*)(hb + (size_t)mA.x * DF + q * 4);
        uint2 pB = *(const uint2*)(hb + (size_t)mB.x * DF + q * 4);
        uint2 pC = *(const uint2*)(hb + (size_t)mC.x * DF + q * 4);
        uint2 pD = *(const uint2*)(hb + (size_t)mD.x * DF + q * 4);
        acc.x = fmaxf(acc.x, __uint_as_float(pA.x << 16)          * wA);
        acc.y = fmaxf(acc.y, __uint_as_float(pA.x & 0xffff0000u)  * wA);
        acc.z = fmaxf(acc.z, __uint_as_float(pA.y << 16)          * wA);
        acc.w = fmaxf(acc.w, __uint_as_float(pA.y & 0xffff0000u)  * wA);
        acc.x = fmaxf(acc.x, __uint_as_float(pB.x << 16)          * wB);
        acc.y = fmaxf(acc.y, __uint_as_float(pB.x & 0xffff0000u)  * wB);
        acc.z = fmaxf(acc.z, __uint_as_float(pB.y << 16)          * wB);
        acc.w = fmaxf(acc.w, __uint_as_float(pB.y & 0xffff0000u)  * wB);
        acc.x = fmaxf(acc.x, __uint_as_float(pC.x << 16)          * wC);
        acc.y = fmaxf(acc.y, __uint_as_float(pC.x & 0xffff0000u)  * wC);
        acc.z = fmaxf(acc.z, __uint_as_float(pC.y << 16)          * wC);
        acc.w = fmaxf(acc.w, __uint_as_float(pC.y & 0xffff0000u)  * wC);
        acc.x = fmaxf(acc.x, __uint_as_float(pD.x << 16)          * wD);
        acc.y = fmaxf(acc.y, __uint_as_float(pD.x & 0xffff0000u)  * wD);
        acc.z = fmaxf(acc.z, __uint_as_float(pD.y << 16)          * wD);
        acc.w = fmaxf(acc.w, __uint_as_float(pD.y & 0xffff0000u)  * wD);
    }

    float4 o;
    o.x = fmaxf(acc.x, __shfl_xor(acc.x, 32));
    o.y = fmaxf(acc.y, __shfl_xor(acc.y, 32));
    o.z = fmaxf(acc.z, __shfl_xor(acc.z, 32));
    o.w = fmaxf(acc.w, __shfl_xor(acc.w, 32));
    if (beg == end) o = make_float4(0.f, 0.f, 0.f, 0.f);
    if (half == 0) {
        ushort4 ob;
        ob.x = f2bf(o.x); ob.y = f2bf(o.y); ob.z = f2bf(o.z); ob.w = f2bf(o.w);
        *(ushort4*)(neighb + (size_t)node * DF + q * 4) = ob;
    }
}

// ================= K4: out = featb@Wn1^T + neighb@Wn2^T + b_neigh (fp32) ====
__global__ __launch_bounds__(256) void gemm_out(
    const unsigned short* __restrict__ featb,
    const unsigned short* __restrict__ neighb,
    const unsigned short* __restrict__ Wn1_f,
    const unsigned short* __restrict__ Wn2_f,
    const float* __restrict__ bias,
    float* __restrict__ out)
{
    int wave = (blockIdx.x * 256 + threadIdx.x) >> 6;
    int lane = threadIdx.x & 63;
    int m0 = wave * 16;
    if (m0 >= N_NODES) return;
    const int n = lane & 15, quad = lane >> 4;

    f32x4 acc[8];
    #pragma unroll
    for (int c = 0; c < 8; ++c) {
        float bv = bias[c * 16 + n];
        acc[c] = (f32x4){bv, bv, bv, bv};
    }

    const unsigned short* a0 = featb  + (size_t)(m0 + n) * DF + quad * 8;
    const unsigned short* a1 = neighb + (size_t)(m0 + n) * DF + quad * 8;
    #pragma unroll
    for (int t = 0; t < 4; ++t) {
        bf16x8 af = *(const bf16x8*)(a0 + t * 32);
        #pragma unroll
        for (int c = 0; c < 8; ++c) {
            bf16x8 bf = *(const bf16x8*)(Wn1_f + (size_t)((c * 4 + t) * 64 + lane) * 8);
            acc[c] = __builtin_amdgcn_mfma_f32_16x16x32_bf16(af, bf, acc[c], 0, 0, 0);
        }
    }
    #pragma unroll
    for (int t = 0; t < 4; ++t) {
        bf16x8 af = *(const bf16x8*)(a1 + t * 32);
        #pragma unroll
        for (int c = 0; c < 8; ++c) {
            bf16x8 bf = *(const bf16x8*)(Wn2_f + (size_t)((c * 4 + t) * 64 + lane) * 8);
            acc[c] = __builtin_amdgcn_mfma_f32_16x16x32_bf16(af, bf, acc[c], 0, 0, 0);
        }
    }

    #pragma unroll
    for (int c = 0; c < 8; ++c)
        #pragma unroll
        for (int r = 0; r < 4; ++r)
            out[(size_t)(m0 + quad * 4 + r) * DF + c * 16 + n] = acc[c][r];
}

extern "C" void kernel_launch(void* const* d_in, const int* in_sizes, int n_in,
                              void* d_out, int out_size, void* d_ws, size_t ws_size,
                              hipStream_t stream) {
    const float* feat    = (const float*)d_in[0];
    const float* weight  = (const float*)d_in[1];
    const int*   src     = (const int*)d_in[2];
    const int*   dst     = (const int*)d_in[3];
    const float* W_pool  = (const float*)d_in[4];
    const float* b_pool  = (const float*)d_in[5];
    const float* W_neigh = (const float*)d_in[6];
    const float* b_neigh = (const float*)d_in[7];
    float* out = (float*)d_out;

    char* ws = (char*)d_ws;
    unsigned short* featb  = (unsigned short*)(ws);              // 12,800,000 B
    unsigned short* hb     = (unsigned short*)(ws + 12800000);   // 12,800,000 B
    unsigned short* neighb = (unsigned short*)(ws + 25600000);   // 12,800,000 B
    unsigned short* Wp_f   = (unsigned short*)(ws + 38400000);   // 32,768 B
    unsigned short* Wn1_f  = (unsigned short*)(ws + 38432768);   // 32,768 B
    unsigned short* Wn2_f  = (unsigned short*)(ws + 38465536);   // 32,768 B
    int*   offsets   = (int*)  (ws + 38498304);                  // 200,064 B
    int*   bucketcnt = (int*)  (ws + 38698368);                  // 1,024 B
    uint2* staging   = (uint2*)(ws + 38699392);                  // 9,633,792 B
    uint2* edges     = (uint2*)(ws + 48333184);                  // 5,120,000 B -> ~53.5 MB

    hipMemsetAsync(bucketcnt, 0, 1024, stream);

    // K1: PassA (coarse bucket scatter) || featb conversion || W fragments
    const int K1_BLOCKS = PA_BLOCKS + NF4 / 256 + NWG / 256;   // 250+6250+24
    k1_setup_bucket<<<K1_BLOCKS, 256, 0, stream>>>(
        feat, W_pool, W_neigh, src, dst, weight,
        featb, Wp_f, Wn1_f, Wn2_f, bucketcnt, staging);

    // K2: gemm_pool (hb) || PassB (offsets + final dst-sorted edges)
    k2_gemm_passb<<<GEMMB + NBUCK, 1024, 0, stream>>>(
        featb, Wp_f, b_pool, hb, bucketcnt, staging, offsets, edges);

    // K3: neighb = bf16(segment_max(hb[src]*w, dst)), 0 for empty
    neigh_max_kernel<<<(N_NODES + 3) / 4, 256, 0, stream>>>(hb, offsets, edges, neighb);

    // K4: out = featb @ Wn1^T + neighb @ Wn2^T + b_neigh
    gemm_out<<<782, 256, 0, stream>>>(
        featb, neighb, Wn1_f, Wn2_f, b_neigh, out);
}